// Round 1
// baseline (820.725 us; speedup 1.0000x reference)
//
#include <hip/hip_runtime.h>

#define B_  16
#define G_  4
#define CG  64
#define H_  64
#define W_  64
#define KK  9
#define HW  (H_ * W_)
#define OWS 20   // padded j-stride for owT (18 -> 20 for 16B alignment)

// ---------------------------------------------------------------------------
// Weight transpose into workspace:
//   dwT[g][k][i][o] = def_w[g][o][i][k]      (G*KK*CG*CG = 147456 floats)
//   owT[g][i][rc][j] = off_w[g][j][i][rc]    padded to OWS=20 per row (46080)
// ---------------------------------------------------------------------------
__global__ void transpose_weights(const float* __restrict__ off_w,
                                  const float* __restrict__ def_w,
                                  float* __restrict__ dwT,
                                  float* __restrict__ owT,
                                  int total)
{
    int tid = blockIdx.x * 256 + threadIdx.x;
    const int ndw = G_ * KK * CG * CG;      // 147456
    if (tid < ndw) {
        int o = tid & 63;
        int i = (tid >> 6) & 63;
        int k = (tid >> 12) % KK;
        int g = tid / (KK * CG * CG);
        dwT[tid] = def_w[((g * CG + o) * CG + i) * KK + k];
    } else if (tid < total) {
        int t2 = tid - ndw;
        int j  = t2 % OWS;
        int rc = (t2 / OWS) % 9;
        int i  = (t2 / (OWS * 9)) % CG;
        int g  = t2 / (OWS * 9 * CG);
        owT[t2] = (j < 18) ? off_w[((g * 18 + j) * CG + i) * 9 + rc] : 0.0f;
    }
}

// ---------------------------------------------------------------------------
// Fused deformable conv. Block = (b, g, h). 256 threads.
// Phase A: offset conv (i split over 4 waves, 18 acc/thread, LDS reduce)
// Phase B: per tap k: bilinear gather -> LDS, dwT stage -> LDS, 4x4 einsum
// ---------------------------------------------------------------------------
template <bool USE_WS>
__global__ __launch_bounds__(256, 4)
void deform_kernel(const float* __restrict__ x,
                   const float* __restrict__ off_w,
                   const float* __restrict__ off_b,
                   const float* __restrict__ def_w,
                   const float* __restrict__ def_b,
                   const float* __restrict__ dwT,
                   const float* __restrict__ owT,
                   float* __restrict__ out)
{
    const int blk = blockIdx.x;
    const int h = blk & 63;
    const int g = (blk >> 6) & 3;
    const int b = blk >> 8;

    __shared__ float pys[KK][W_];
    __shared__ float pxs[KK][W_];
    __shared__ float buf[8192];          // 32KB, multi-purpose
    float* red   = buf;                  // [4][18][64] phase-A reduction
    float* s_lds = buf;                  // [64][64]  sampled (i, w)
    float* dwTl  = buf + 4096;           // [64][64]  weights (i, o)

    const int t = threadIdx.x;
    const int w = t & 63;
    const int p = t >> 6;                // wave id (0..3), uniform per wave

    const float* xg = x + (size_t)(b * 256 + g * 64) * HW;

    // ---------------- Phase A: offset conv ----------------
    float acc[18];
#pragma unroll
    for (int j = 0; j < 18; j++) acc[j] = 0.0f;

    {
        const int i0 = p * 16;
        for (int ii = 0; ii < 16; ii++) {
            const int i = i0 + ii;
            const float* xi = xg + i * HW;
#pragma unroll
            for (int r = 0; r < 3; r++) {
                const int y = h + r - 1;
                if ((unsigned)y >= (unsigned)H_) continue;   // zero pad
#pragma unroll
                for (int c = 0; c < 3; c++) {
                    const int xc = w + c - 1;
                    const float xv =
                        ((unsigned)xc < (unsigned)W_) ? xi[y * W_ + xc] : 0.0f;
                    if (USE_WS) {
                        const float* owp = owT + ((g * CG + i) * 9 + (r * 3 + c)) * OWS;
                        const float4 w0 = *(const float4*)(owp + 0);
                        const float4 w1 = *(const float4*)(owp + 4);
                        const float4 w2 = *(const float4*)(owp + 8);
                        const float4 w3 = *(const float4*)(owp + 12);
                        const float  wa = owp[16], wb = owp[17];
                        acc[0]  = fmaf(w0.x, xv, acc[0]);
                        acc[1]  = fmaf(w0.y, xv, acc[1]);
                        acc[2]  = fmaf(w0.z, xv, acc[2]);
                        acc[3]  = fmaf(w0.w, xv, acc[3]);
                        acc[4]  = fmaf(w1.x, xv, acc[4]);
                        acc[5]  = fmaf(w1.y, xv, acc[5]);
                        acc[6]  = fmaf(w1.z, xv, acc[6]);
                        acc[7]  = fmaf(w1.w, xv, acc[7]);
                        acc[8]  = fmaf(w2.x, xv, acc[8]);
                        acc[9]  = fmaf(w2.y, xv, acc[9]);
                        acc[10] = fmaf(w2.z, xv, acc[10]);
                        acc[11] = fmaf(w2.w, xv, acc[11]);
                        acc[12] = fmaf(w3.x, xv, acc[12]);
                        acc[13] = fmaf(w3.y, xv, acc[13]);
                        acc[14] = fmaf(w3.z, xv, acc[14]);
                        acc[15] = fmaf(w3.w, xv, acc[15]);
                        acc[16] = fmaf(wa,  xv, acc[16]);
                        acc[17] = fmaf(wb,  xv, acc[17]);
                    } else {
#pragma unroll
                        for (int j = 0; j < 18; j++) {
                            const float wv = off_w[((g * 18 + j) * CG + i) * 9 + r * 3 + c];
                            acc[j] = fmaf(wv, xv, acc[j]);
                        }
                    }
                }
            }
        }
    }

    // cross-wave reduce + build sample coordinates
#pragma unroll
    for (int j = 0; j < 18; j++) red[(p * 18 + j) * 64 + w] = acc[j];
    __syncthreads();

    for (int idx = t; idx < 18 * 64; idx += 256) {
        const int j  = idx >> 6;
        const int ww = idx & 63;
        float v = red[(0 * 18 + j) * 64 + ww] + red[(1 * 18 + j) * 64 + ww]
                + red[(2 * 18 + j) * 64 + ww] + red[(3 * 18 + j) * 64 + ww];
        v += off_b[g * 18 + j];
        const int k = j >> 1;
        if ((j & 1) == 0) {
            pys[k][ww] = v + (float)(k / 3 - 1) + (float)h;
        } else {
            pxs[k][ww] = v + (float)(k % 3 - 1) + (float)ww;
        }
    }
    __syncthreads();

    // ---------------- Phase B: gather + einsum over taps ----------------
    float facc[16];
#pragma unroll
    for (int q = 0; q < 16; q++) facc[q] = 0.0f;

    const int w4 = (t & 15) << 2;
    const int o4 = (t >> 4) << 2;

    for (int k = 0; k < KK; k++) {
        // stage dwT[g][k][.][.] -> LDS [i][o]
        if (USE_WS) {
            const float* src = dwT + (size_t)(g * KK + k) * CG * CG;
#pragma unroll
            for (int n = 0; n < 16; n++) dwTl[t + 256 * n] = src[t + 256 * n];
        } else {
#pragma unroll
            for (int n = 0; n < 16; n++) {
                const int v = t + 256 * n;
                const int i = v >> 6;
                const int o = v & 63;
                dwTl[v] = def_w[((g * CG + o) * CG + i) * KK + k];
            }
        }

        // bilinear gather -> s_lds[i][w]
        const float py  = pys[k][w];
        const float px  = pxs[k][w];
        const float y0f = floorf(py);
        const float x0f = floorf(px);
        const float wy  = py - y0f;
        const float wx  = px - x0f;
        const int   y0  = (int)y0f;
        const int   x0  = (int)x0f;
        const float w00 = (1.0f - wy) * (1.0f - wx);
        const float w01 = (1.0f - wy) * wx;
        const float w10 = wy * (1.0f - wx);
        const float w11 = wy * wx;
        const bool vy0 = (unsigned)y0       < (unsigned)H_;
        const bool vy1 = (unsigned)(y0 + 1) < (unsigned)H_;
        const bool vx0 = (unsigned)x0       < (unsigned)W_;
        const bool vx1 = (unsigned)(x0 + 1) < (unsigned)W_;
        const int a00 = y0 * W_ + x0;

#pragma unroll
        for (int n = 0; n < 16; n++) {
            const int i = (n << 2) + p;
            const float* xi = xg + i * HW;
            const float v00 = (vy0 && vx0) ? xi[a00]          : 0.0f;
            const float v01 = (vy0 && vx1) ? xi[a00 + 1]      : 0.0f;
            const float v10 = (vy1 && vx0) ? xi[a00 + W_]     : 0.0f;
            const float v11 = (vy1 && vx1) ? xi[a00 + W_ + 1] : 0.0f;
            s_lds[i * 64 + w] = w00 * v00 + w01 * v01 + w10 * v10 + w11 * v11;
        }
        __syncthreads();

        // 4x4 micro-tile einsum: facc[oo][ww] += dwTl[i][o4+oo] * s_lds[i][w4+ww]
#pragma unroll 4
        for (int i = 0; i < CG; i++) {
            const float4 sv = *(const float4*)&s_lds[i * 64 + w4];
            const float4 dv = *(const float4*)&dwTl[i * 64 + o4];
            facc[0]  = fmaf(dv.x, sv.x, facc[0]);
            facc[1]  = fmaf(dv.x, sv.y, facc[1]);
            facc[2]  = fmaf(dv.x, sv.z, facc[2]);
            facc[3]  = fmaf(dv.x, sv.w, facc[3]);
            facc[4]  = fmaf(dv.y, sv.x, facc[4]);
            facc[5]  = fmaf(dv.y, sv.y, facc[5]);
            facc[6]  = fmaf(dv.y, sv.z, facc[6]);
            facc[7]  = fmaf(dv.y, sv.w, facc[7]);
            facc[8]  = fmaf(dv.z, sv.x, facc[8]);
            facc[9]  = fmaf(dv.z, sv.y, facc[9]);
            facc[10] = fmaf(dv.z, sv.z, facc[10]);
            facc[11] = fmaf(dv.z, sv.w, facc[11]);
            facc[12] = fmaf(dv.w, sv.x, facc[12]);
            facc[13] = fmaf(dv.w, sv.y, facc[13]);
            facc[14] = fmaf(dv.w, sv.z, facc[14]);
            facc[15] = fmaf(dv.w, sv.w, facc[15]);
        }
        __syncthreads();
    }

    // ---------------- epilogue: bias + store ----------------
    float* outp = out + (size_t)(b * 256 + g * 64) * HW + h * W_;
#pragma unroll
    for (int oo = 0; oo < 4; oo++) {
        const int o = o4 + oo;
        const float bias = def_b[g * 64 + o];
        float4 r;
        r.x = facc[oo * 4 + 0] + bias;
        r.y = facc[oo * 4 + 1] + bias;
        r.z = facc[oo * 4 + 2] + bias;
        r.w = facc[oo * 4 + 3] + bias;
        *(float4*)&outp[o * HW + w4] = r;
    }
}

// ---------------------------------------------------------------------------
extern "C" void kernel_launch(void* const* d_in, const int* in_sizes, int n_in,
                              void* d_out, int out_size, void* d_ws, size_t ws_size,
                              hipStream_t stream)
{
    (void)in_sizes; (void)n_in; (void)out_size;
    const float* x     = (const float*)d_in[0];
    const float* off_w = (const float*)d_in[1];
    const float* off_b = (const float*)d_in[2];
    const float* def_w = (const float*)d_in[3];
    const float* def_b = (const float*)d_in[4];
    float* out = (float*)d_out;

    const int ndw   = G_ * KK * CG * CG;        // 147456
    const int now   = G_ * CG * 9 * OWS;        // 46080
    const int total = ndw + now;                // 193536
    const size_t need = (size_t)total * sizeof(float);

    const int nblk = B_ * G_ * H_;              // 4096

    if (ws_size >= need) {
        float* dwT = (float*)d_ws;
        float* owT = dwT + ndw;
        transpose_weights<<<(total + 255) / 256, 256, 0, stream>>>(off_w, def_w, dwT, owT, total);
        deform_kernel<true><<<nblk, 256, 0, stream>>>(x, off_w, off_b, def_w, def_b,
                                                      dwT, owT, out);
    } else {
        deform_kernel<false><<<nblk, 256, 0, stream>>>(x, off_w, off_b, def_w, def_b,
                                                       nullptr, nullptr, out);
    }
}

// Round 2
// 777.109 us; speedup vs baseline: 1.0561x; 1.0561x over previous
//
#include <hip/hip_runtime.h>
#include <hip/hip_bf16.h>

#define B_  16
#define G_  4
#define CG  64
#define H_  64
#define W_  64
#define KK  9
#define HW  (H_ * W_)
#define OWS 20   // padded j-stride for owT (18 -> 20 for 16B alignment)
#define IP  72   // padded i-stride (shorts) for bf16 [.][i] tiles: 144B rows

typedef short short8 __attribute__((ext_vector_type(8)));
typedef float f32x4  __attribute__((ext_vector_type(4)));

__device__ __forceinline__ short f2bf(float v) {
    __hip_bfloat16 hb = __float2bfloat16(v);
    short s;
    __builtin_memcpy(&s, &hb, 2);
    return s;
}

// ---------------------------------------------------------------------------
// Weight prep into workspace:
//   dwA[g][k][o][ip] (bf16, ip padded to 72)  = def_w[g][o][i][k]   (A operand)
//   owT[g][i][rc][j] (fp32, j padded to 20)   = off_w[g][j][i][rc]
// ---------------------------------------------------------------------------
__global__ void transpose_weights(const float* __restrict__ off_w,
                                  const float* __restrict__ def_w,
                                  short* __restrict__ dwA,
                                  float* __restrict__ owT,
                                  int total)
{
    int tid = blockIdx.x * 256 + threadIdx.x;
    const int ndwA = G_ * KK * CG * IP;     // 165888
    if (tid < ndwA) {
        int ip = tid % IP;
        int o  = (tid / IP) & 63;
        int k  = (tid / (IP * CG)) % KK;
        int g  = tid / (IP * CG * KK);
        float v = (ip < CG) ? def_w[((g * CG + o) * CG + ip) * KK + k] : 0.0f;
        dwA[tid] = f2bf(v);
    } else if (tid < total) {
        int t2 = tid - ndwA;
        int j  = t2 % OWS;
        int rc = (t2 / OWS) % 9;
        int i  = (t2 / (OWS * 9)) % CG;
        int g  = t2 / (OWS * 9 * CG);
        owT[t2] = (j < 18) ? off_w[((g * 18 + j) * CG + i) * 9 + rc] : 0.0f;
    }
}

// ---------------------------------------------------------------------------
// Fused deformable conv. Block = (b, g, h) with XCD swizzle. 256 threads.
// Phase A: offset conv fp32 (i split over 4 waves, 18 acc/thread, LDS reduce)
// Phase B: per tap k: bilinear gather -> bf16 LDS sT[w][i], MFMA 16x16x32 einsum
// ---------------------------------------------------------------------------
template <bool USE_WS>
__global__ __launch_bounds__(256, 4)
void deform_kernel(const float* __restrict__ x,
                   const float* __restrict__ off_w,
                   const float* __restrict__ off_b,
                   const float* __restrict__ def_w,
                   const float* __restrict__ def_b,
                   const short* __restrict__ dwA,
                   const float* __restrict__ owT,
                   float* __restrict__ out)
{
    // XCD-aware swizzle: low 3 bits pick (b,g) stream -> each XCD L2 sees
    // ~8 x-slices sequentially instead of all 64.
    const int raw = blockIdx.x;
    const int r8  = raw & 7;
    const int h   = (raw >> 3) & 63;
    const int q8  = raw >> 9;
    const int bg  = q8 * 8 + r8;
    const int b   = bg >> 2;
    const int g   = bg & 3;

    __shared__ float pys[KK][W_];
    __shared__ float pxs[KK][W_];
    __shared__ alignas(16) char smem[18432];   // red [4][18][64] f32 / sT [64][IP] bf16
    float* red = (float*)smem;
    short* sT  = (short*)smem;

    const int t = threadIdx.x;
    const int w = t & 63;
    const int p = t >> 6;                // wave id (0..3), uniform per wave

    const float* xg = x + (size_t)(b * 256 + g * 64) * HW;

    // ---------------- Phase A: offset conv (fp32 VALU) ----------------
    float acc[18];
#pragma unroll
    for (int j = 0; j < 18; j++) acc[j] = 0.0f;

    {
        const int i0 = p * 16;
        for (int ii = 0; ii < 16; ii++) {
            const int i = i0 + ii;
            const float* xi = xg + i * HW;
#pragma unroll
            for (int r = 0; r < 3; r++) {
                const int y = h + r - 1;
                if ((unsigned)y >= (unsigned)H_) continue;   // zero pad
#pragma unroll
                for (int c = 0; c < 3; c++) {
                    const int xc = w + c - 1;
                    const float xv =
                        ((unsigned)xc < (unsigned)W_) ? xi[y * W_ + xc] : 0.0f;
                    if (USE_WS) {
                        const float* owp = owT + ((g * CG + i) * 9 + (r * 3 + c)) * OWS;
                        const float4 w0 = *(const float4*)(owp + 0);
                        const float4 w1 = *(const float4*)(owp + 4);
                        const float4 w2 = *(const float4*)(owp + 8);
                        const float4 w3 = *(const float4*)(owp + 12);
                        const float  wa = owp[16], wb = owp[17];
                        acc[0]  = fmaf(w0.x, xv, acc[0]);
                        acc[1]  = fmaf(w0.y, xv, acc[1]);
                        acc[2]  = fmaf(w0.z, xv, acc[2]);
                        acc[3]  = fmaf(w0.w, xv, acc[3]);
                        acc[4]  = fmaf(w1.x, xv, acc[4]);
                        acc[5]  = fmaf(w1.y, xv, acc[5]);
                        acc[6]  = fmaf(w1.z, xv, acc[6]);
                        acc[7]  = fmaf(w1.w, xv, acc[7]);
                        acc[8]  = fmaf(w2.x, xv, acc[8]);
                        acc[9]  = fmaf(w2.y, xv, acc[9]);
                        acc[10] = fmaf(w2.z, xv, acc[10]);
                        acc[11] = fmaf(w2.w, xv, acc[11]);
                        acc[12] = fmaf(w3.x, xv, acc[12]);
                        acc[13] = fmaf(w3.y, xv, acc[13]);
                        acc[14] = fmaf(w3.z, xv, acc[14]);
                        acc[15] = fmaf(w3.w, xv, acc[15]);
                        acc[16] = fmaf(wa,  xv, acc[16]);
                        acc[17] = fmaf(wb,  xv, acc[17]);
                    } else {
#pragma unroll
                        for (int j = 0; j < 18; j++) {
                            const float wv = off_w[((g * 18 + j) * CG + i) * 9 + r * 3 + c];
                            acc[j] = fmaf(wv, xv, acc[j]);
                        }
                    }
                }
            }
        }
    }

    // cross-wave reduce + build sample coordinates
#pragma unroll
    for (int j = 0; j < 18; j++) red[(p * 18 + j) * 64 + w] = acc[j];
    __syncthreads();

    for (int idx = t; idx < 18 * 64; idx += 256) {
        const int j  = idx >> 6;
        const int ww = idx & 63;
        float v = red[(0 * 18 + j) * 64 + ww] + red[(1 * 18 + j) * 64 + ww]
                + red[(2 * 18 + j) * 64 + ww] + red[(3 * 18 + j) * 64 + ww];
        v += off_b[g * 18 + j];
        const int k = j >> 1;
        if ((j & 1) == 0) {
            pys[k][ww] = v + (float)(k / 3 - 1) + (float)h;
        } else {
            pxs[k][ww] = v + (float)(k % 3 - 1) + (float)ww;
        }
    }
    __syncthreads();

    // ---------------- Phase B: gather (bf16) + MFMA einsum over taps ----------
    const int lane = t & 63;
    const int nn   = lane & 15;      // column within 16-tile
    const int qq   = lane >> 4;      // quad
    const int o0   = p * 16;         // this wave's output-row tile

    f32x4 accd[4];
#pragma unroll
    for (int wt = 0; wt < 4; wt++) accd[wt] = (f32x4){0.f, 0.f, 0.f, 0.f};

    const short* dwAg = dwA + (size_t)g * KK * CG * IP;

    for (int k = 0; k < KK; k++) {
        // bilinear gather -> sT[w][i] bf16 (two 8-channel chunks per thread)
        const float py  = pys[k][w];
        const float px  = pxs[k][w];
        const float y0f = floorf(py);
        const float x0f = floorf(px);
        const float wy  = py - y0f;
        const float wx  = px - x0f;
        const int   y0  = (int)y0f;
        const int   x0  = (int)x0f;
        const float w00 = (1.0f - wy) * (1.0f - wx);
        const float w01 = (1.0f - wy) * wx;
        const float w10 = wy * (1.0f - wx);
        const float w11 = wy * wx;
        const bool vy0 = (unsigned)y0       < (unsigned)H_;
        const bool vy1 = (unsigned)(y0 + 1) < (unsigned)H_;
        const bool vx0 = (unsigned)x0       < (unsigned)W_;
        const bool vx1 = (unsigned)(x0 + 1) < (unsigned)W_;
        const int a00 = y0 * W_ + x0;

#pragma unroll
        for (int cc = 0; cc < 2; cc++) {
            const int c = p + cc * 4;            // chunk of 8 channels
            short8 pk;
#pragma unroll
            for (int e = 0; e < 8; e++) {
                const float* xi = xg + (c * 8 + e) * HW + a00;
                const float v00 = (vy0 && vx0) ? xi[0]      : 0.0f;
                const float v01 = (vy0 && vx1) ? xi[1]      : 0.0f;
                const float v10 = (vy1 && vx0) ? xi[W_]     : 0.0f;
                const float v11 = (vy1 && vx1) ? xi[W_ + 1] : 0.0f;
                const float sv = w00 * v00 + w01 * v01 + w10 * v10 + w11 * v11;
                pk[e] = f2bf(sv);
            }
            *(short8*)&sT[w * IP + c * 8] = pk;
        }
        __syncthreads();

        // einsum via MFMA 16x16x32 bf16:
        //   out[o][w] += sum_i dw_k[i][o] * s_k[i][w]
        //   A[m=o][k=i] = dwA[g][k][o][i];  B[k=i][n=w] = sT[w][i] (frag-native)
        const short* dwAk = dwAg + k * CG * IP;
#pragma unroll
        for (int K0 = 0; K0 < 2; K0++) {
            const int ch = K0 * 4 + qq;          // 8-element K-chunk index
            short8 afrag;
            if (USE_WS) {
                afrag = *(const short8*)&dwAk[(o0 + nn) * IP + ch * 8];
            } else {
#pragma unroll
                for (int j = 0; j < 8; j++) {
                    afrag[j] = f2bf(def_w[((g * CG + o0 + nn) * CG + ch * 8 + j) * KK + k]);
                }
            }
#pragma unroll
            for (int wt = 0; wt < 4; wt++) {
                const short8 bfrag = *(const short8*)&sT[(wt * 16 + nn) * IP + ch * 8];
                accd[wt] = __builtin_amdgcn_mfma_f32_16x16x32_bf16(afrag, bfrag, accd[wt], 0, 0, 0);
            }
        }
        __syncthreads();
    }

    // ---------------- epilogue: bias + store ----------------
    // C/D layout: col = lane&15 (w), row = qq*4 + reg (o within tile)
    float* outb = out + (size_t)(b * 256 + g * 64) * HW + h * W_;
    float bias[4];
#pragma unroll
    for (int rr = 0; rr < 4; rr++) bias[rr] = def_b[g * 64 + o0 + qq * 4 + rr];
#pragma unroll
    for (int wt = 0; wt < 4; wt++) {
#pragma unroll
        for (int rr = 0; rr < 4; rr++) {
            const int o = o0 + qq * 4 + rr;
            outb[(size_t)o * HW + wt * 16 + nn] = accd[wt][rr] + bias[rr];
        }
    }
}

// ---------------------------------------------------------------------------
extern "C" void kernel_launch(void* const* d_in, const int* in_sizes, int n_in,
                              void* d_out, int out_size, void* d_ws, size_t ws_size,
                              hipStream_t stream)
{
    (void)in_sizes; (void)n_in; (void)out_size;
    const float* x     = (const float*)d_in[0];
    const float* off_w = (const float*)d_in[1];
    const float* off_b = (const float*)d_in[2];
    const float* def_w = (const float*)d_in[3];
    const float* def_b = (const float*)d_in[4];
    float* out = (float*)d_out;

    const int ndwA  = G_ * KK * CG * IP;        // 165888 shorts
    const int now   = G_ * CG * 9 * OWS;        // 46080 floats
    const int total = ndwA + now;               // thread count for prep
    const size_t need = (size_t)ndwA * 2 + (size_t)now * 4;   // 516096 B

    const int nblk = B_ * G_ * H_;              // 4096

    if (ws_size >= need) {
        short* dwA = (short*)d_ws;
        float* owT = (float*)((char*)d_ws + (size_t)ndwA * 2);
        transpose_weights<<<(total + 255) / 256, 256, 0, stream>>>(off_w, def_w, dwA, owT, total);
        deform_kernel<true><<<nblk, 256, 0, stream>>>(x, off_w, off_b, def_w, def_b,
                                                      dwA, owT, out);
    } else {
        deform_kernel<false><<<nblk, 256, 0, stream>>>(x, off_w, off_b, def_w, def_b,
                                                       nullptr, nullptr, out);
    }
}

// Round 4
// 259.905 us; speedup vs baseline: 3.1578x; 2.9900x over previous
//
#include <hip/hip_runtime.h>
#include <hip/hip_bf16.h>

#define B_  16
#define G_  4
#define CG  64
#define H_  64
#define W_  64
#define KK  9
#define HW  (H_ * W_)
#define IP  72            // padded i-stride (shorts) for sT rows: 144 B
#define PD  68            // padded spatial dim (64 + 2 each side)
#define XSLICE (PD * PD * CG)   // shorts per (b,g) slice of xTpad

typedef short  short8  __attribute__((ext_vector_type(8)));
typedef float  f32x4   __attribute__((ext_vector_type(4)));
typedef float  f32x16  __attribute__((ext_vector_type(16)));

__device__ __forceinline__ short f2bf(float v) {
    __hip_bfloat16 hb = __float2bfloat16(v);
    short s;
    __builtin_memcpy(&s, &hb, 2);
    return s;
}
__device__ __forceinline__ float bfu(unsigned short s) {
    unsigned int u = ((unsigned int)s) << 16;
    float f;
    __builtin_memcpy(&f, &u, 4);
    return f;
}

// ---------------------------------------------------------------------------
// P1: weight prep.
//  dwA32[g][k][mt][step][q2][o][e] bf16 = def_w[g][mt*32+o][i=step*16+q2*8+e][k]
//      per (g,k): 4096 elems (mt:2, step:4, q2:2? no - q2 is 1 bit, o:32, e:8)
//      total ndw = G*KK*4096 = 147456
//  owA  [g][s][tm][q][jj][e]  bf16 = off_w[g][j=tm*16+jj][i][rc]       (73728)
//        with rc = s>>1, i = (s&1)*32 + q*8 + e, zero for j >= 18
// ---------------------------------------------------------------------------
__global__ void prep_weights(const float* __restrict__ off_w,
                             const float* __restrict__ def_w,
                             short* __restrict__ dwA32,
                             short* __restrict__ owA)
{
    const int tid = blockIdx.x * 256 + threadIdx.x;
    const int ndw = G_ * KK * 4096;               // 147456
    const int now = G_ * 18 * 2 * 4 * 16 * 8;     // 73728
    if (tid < ndw) {
        const int e    = tid & 7;
        const int o    = (tid >> 3) & 31;
        const int q2   = (tid >> 8) & 1;
        const int step = (tid >> 9) & 3;
        const int mt   = (tid >> 11) & 1;
        const int gk   = tid >> 12;
        const int k    = gk % KK;
        const int g    = gk / KK;
        const int oo   = mt * 32 + o;
        const int i    = step * 16 + q2 * 8 + e;
        dwA32[tid] = f2bf(def_w[((g * CG + oo) * CG + i) * KK + k]);
    } else if (tid < ndw + now) {
        const int t2 = tid - ndw;
        const int e  = t2 & 7;
        const int jj = (t2 >> 3) & 15;
        const int q  = (t2 >> 7) & 3;
        const int tm = (t2 >> 9) & 1;
        const int gs = t2 >> 10;
        const int s  = gs % 18;
        const int g  = gs / 18;
        const int j  = tm * 16 + jj;
        const int rc = s >> 1;
        const int i  = (s & 1) * 32 + q * 8 + e;
        owA[t2] = (j < 18) ? f2bf(off_w[((g * 18 + j) * CG + i) * KK + rc]) : (short)0;
    }
}

// ---------------------------------------------------------------------------
// P2: x -> xTpad[b][g][yp 0..67][xp 0..67][i 0..63] bf16, zero borders (pad 2).
// Grid (68, 64): blockIdx.x = yp, blockIdx.y = bg. 256 threads.
// ---------------------------------------------------------------------------
__global__ void prep_x(const float* __restrict__ x, short* __restrict__ xTpad)
{
    const int yp = blockIdx.x;
    const int bg = blockIdx.y;
    const int t  = threadIdx.x;
    short* dst = xTpad + (size_t)bg * XSLICE + (size_t)yp * PD * CG;

    if (yp < 2 || yp >= 66) {
        const int4 z = {0, 0, 0, 0};
        for (int c = t; c < (PD * CG * 2) / 16; c += 256)   // 544 16B chunks
            ((int4*)dst)[c] = z;
        return;
    }

    __shared__ float sRow[CG][65];
    const int yy = yp - 2;
    const float* src = x + (size_t)bg * CG * HW + (size_t)yy * W_;
    {
        const int i  = t >> 2;
        const int x0 = (t & 3) * 16;
        const float* sp = src + (size_t)i * HW + x0;
#pragma unroll
        for (int c = 0; c < 4; c++) {
            const float4 v = ((const float4*)sp)[c];
            sRow[i][x0 + c * 4 + 0] = v.x;
            sRow[i][x0 + c * 4 + 1] = v.y;
            sRow[i][x0 + c * 4 + 2] = v.z;
            sRow[i][x0 + c * 4 + 3] = v.w;
        }
    }
    __syncthreads();

    for (int task = t; task < PD * 8; task += 256) {   // 544 tasks
        const int ich = task & 7;
        const int xp  = task >> 3;
        const int xx  = xp - 2;
        short8 v = {0, 0, 0, 0, 0, 0, 0, 0};
        if ((unsigned)xx < (unsigned)W_) {
#pragma unroll
            for (int e = 0; e < 8; e++) v[e] = f2bf(sRow[ich * 8 + e][xx]);
        }
        *(short8*)(dst + xp * CG + ich * 8) = v;
    }
}

// ---------------------------------------------------------------------------
// Main fused kernel. Block = (b, g, h) with XCD swizzle. 256 threads, 4 waves.
//  Phase A: offset conv via MFMA 16x16x32 (each wave owns a 16-col w-tile,
//           full K=576). No cross-wave reduce.
//  Phase B: per tap: bf16 channel-last gather from xTpad -> sT (double-
//           buffered), einsum via MFMA 32x32x16. One barrier per tap.
// ---------------------------------------------------------------------------
__global__ __launch_bounds__(256, 6)
void deform_main(const short* __restrict__ xTpad,
                 const float* __restrict__ off_b,
                 const float* __restrict__ def_b,
                 const short* __restrict__ dwA32,
                 const short* __restrict__ owA,
                 float* __restrict__ out)
{
    const int raw = blockIdx.x;
    const int r8  = raw & 7;
    const int h   = (raw >> 3) & 63;
    const int q8  = raw >> 9;
    const int bg  = q8 * 8 + r8;
    const int b   = bg >> 2;
    const int g   = bg & 3;

    __shared__ float pys[KK][64];
    __shared__ float pxs[KK][64];
    __shared__ short sT[2][64 * IP];

    const int t    = threadIdx.x;
    const int lane = t & 63;
    const int p    = t >> 6;          // wave id 0..3
    const int nn   = lane & 15;
    const int q    = lane >> 4;

    const short* xb = xTpad + (size_t)bg * XSLICE;

    // ---------------- Phase A: offset conv (MFMA 16x16x32) ----------------
    {
        const short* owAg = owA + g * 18 * 1024;
        f32x4 oa0 = {0.f, 0.f, 0.f, 0.f};
        f32x4 oa1 = {0.f, 0.f, 0.f, 0.f};
#pragma unroll
        for (int s = 0; s < 18; s++) {
            const int rc = s >> 1;
            const int rr = rc / 3;
            const int cc = rc % 3;
            const int ih = (s & 1) * 32;
            const short8 bfr = *(const short8*)(xb
                + ((h + rr + 1) * PD + (p * 16 + nn + cc + 1)) * CG + ih + q * 8);
            const short8 af0 = *(const short8*)(owAg + ((s * 2 + 0) * 4 + q) * 128 + nn * 8);
            const short8 af1 = *(const short8*)(owAg + ((s * 2 + 1) * 4 + q) * 128 + nn * 8);
            oa0 = __builtin_amdgcn_mfma_f32_16x16x32_bf16(af0, bfr, oa0, 0, 0, 0);
            oa1 = __builtin_amdgcn_mfma_f32_16x16x32_bf16(af1, bfr, oa1, 0, 0, 0);
        }
        // C layout: col = nn (w within tile), row = q*4 + reg (j)
        const int n = p * 16 + nn;
#pragma unroll
        for (int reg = 0; reg < 4; reg++) {
            const int j  = q * 4 + reg;
            const int kk = j >> 1;
            const float v = oa0[reg] + off_b[g * 18 + j];
            if ((j & 1) == 0) pys[kk][n] = v + (float)(kk / 3) + (float)(h + 1);
            else              pxs[kk][n] = v + (float)(kk % 3) + (float)(n + 1);
        }
        if (q == 0) {
            const float v16 = oa1[0] + off_b[g * 18 + 16];
            pys[8][n] = v16 + 2.0f + (float)(h + 1);
            const float v17 = oa1[1] + off_b[g * 18 + 17];
            pxs[8][n] = v17 + 2.0f + (float)(n + 1);
        }
        // each wave reads only its own tile's coords in the gather: no barrier
    }

    // ---------------- Phase B: gather + einsum, double-buffered ----------------
    const int mt  = p >> 1;           // einsum output 32-row tile
    const int nt  = p & 1;            // einsum output 32-col tile
    const int n31 = lane & 31;
    const int q2  = lane >> 5;

    f32x16 acc = {0.f};
    const short* dwg = dwA32 + g * KK * 4096;

    // gather of one tap into buffer sTb
    auto gather_tap = [&](int k, short* __restrict__ sTb) {
        const float* pyk = &pys[k][0];
        const float* pxk = &pxs[k][0];
#pragma unroll
        for (int it = 0; it < 4; it++) {
            const int pos = p * 16 + it * 4 + q;
            const float ppy = pyk[pos];
            const float ppx = pxk[pos];
            const float yf = floorf(ppy);
            const float xf = floorf(ppx);
            const float wy = ppy - yf;
            const float wx = ppx - xf;
            int y0 = (int)yf;
            int x0 = (int)xf;
            y0 = (y0 < 0) ? 0 : ((y0 > 66) ? 66 : y0);
            x0 = (x0 < 0) ? 0 : ((x0 > 66) ? 66 : x0);
            const short* cp = xb + (y0 * PD + x0) * CG + nn * 4;
            const ushort4 c00 = *(const ushort4*)cp;
            const ushort4 c01 = *(const ushort4*)(cp + CG);
            const ushort4 c10 = *(const ushort4*)(cp + PD * CG);
            const ushort4 c11 = *(const ushort4*)(cp + (PD + 1) * CG);
            const float w00 = (1.0f - wy) * (1.0f - wx);
            const float w01 = (1.0f - wy) * wx;
            const float w10 = wy * (1.0f - wx);
            const float w11 = wy * wx;
            ushort4 pk;
            pk.x = (unsigned short)f2bf(w00 * bfu(c00.x) + w01 * bfu(c01.x) + w10 * bfu(c10.x) + w11 * bfu(c11.x));
            pk.y = (unsigned short)f2bf(w00 * bfu(c00.y) + w01 * bfu(c01.y) + w10 * bfu(c10.y) + w11 * bfu(c11.y));
            pk.z = (unsigned short)f2bf(w00 * bfu(c00.z) + w01 * bfu(c01.z) + w10 * bfu(c10.z) + w11 * bfu(c11.z));
            pk.w = (unsigned short)f2bf(w00 * bfu(c00.w) + w01 * bfu(c01.w) + w10 * bfu(c10.w) + w11 * bfu(c11.w));
            *(ushort4*)&sTb[pos * IP + nn * 4] = pk;
        }
    };

    // einsum of one tap from buffer sTb (MFMA 32x32x16)
    auto einsum_tap = [&](int k, const short* __restrict__ sTb) {
        const short* dwk = dwg + k * 4096;
#pragma unroll
        for (int step = 0; step < 4; step++) {
            const short8 af = *(const short8*)(dwk + ((mt * 4 + step) * 2 + q2) * 256 + n31 * 8);
            const short8 bf = *(const short8*)&sTb[(nt * 32 + n31) * IP + step * 16 + q2 * 8];
            acc = __builtin_amdgcn_mfma_f32_32x32x16_bf16(af, bf, acc, 0, 0, 0);
        }
    };

    gather_tap(0, &sT[0][0]);
    __syncthreads();
    for (int k = 0; k < KK; k++) {
        if (k < KK - 1) gather_tap(k + 1, &sT[(k + 1) & 1][0]);
        einsum_tap(k, &sT[k & 1][0]);
        __syncthreads();
    }

    // ---------------- epilogue ----------------
    // C/D 32x32 layout: col = lane&31, row = (reg&3) + 8*(reg>>2) + 4*q2
    float* outb = out + (size_t)(b * 256 + g * 64) * HW + h * W_;
    const int n = nt * 32 + n31;
#pragma unroll
    for (int reg = 0; reg < 16; reg++) {
        const int o = mt * 32 + (reg & 3) + 8 * (reg >> 2) + 4 * q2;
        outb[(size_t)o * HW + n] = acc[reg] + def_b[g * 64 + o];
    }
}

// ---------------------------------------------------------------------------
// Fallback (no workspace): round-1-style fused fp32 kernel, known correct.
// ---------------------------------------------------------------------------
__global__ __launch_bounds__(256, 4)
void deform_fallback(const float* __restrict__ x,
                     const float* __restrict__ off_w,
                     const float* __restrict__ off_b,
                     const float* __restrict__ def_w,
                     const float* __restrict__ def_b,
                     float* __restrict__ out)
{
    const int raw = blockIdx.x;
    const int r8  = raw & 7;
    const int h   = (raw >> 3) & 63;
    const int q8  = raw >> 9;
    const int bg  = q8 * 8 + r8;
    const int b   = bg >> 2;
    const int g   = bg & 3;

    __shared__ float pys[KK][W_];
    __shared__ float pxs[KK][W_];
    __shared__ float buf[8192];
    float* red   = buf;
    float* s_lds = buf;
    float* dwTl  = buf + 4096;

    const int t = threadIdx.x;
    const int w = t & 63;
    const int p = t >> 6;

    const float* xg = x + (size_t)(b * 256 + g * 64) * HW;

    float acc[18];
#pragma unroll
    for (int j = 0; j < 18; j++) acc[j] = 0.0f;
    {
        const int i0 = p * 16;
        for (int ii = 0; ii < 16; ii++) {
            const int i = i0 + ii;
            const float* xi = xg + i * HW;
#pragma unroll
            for (int r = 0; r < 3; r++) {
                const int y = h + r - 1;
                if ((unsigned)y >= (unsigned)H_) continue;
#pragma unroll
                for (int c = 0; c < 3; c++) {
                    const int xc = w + c - 1;
                    const float xv = ((unsigned)xc < (unsigned)W_) ? xi[y * W_ + xc] : 0.0f;
#pragma unroll
                    for (int j = 0; j < 18; j++) {
                        const float wv = off_w[((g * 18 + j) * CG + i) * 9 + r * 3 + c];
                        acc[j] = fmaf(wv, xv, acc[j]);
                    }
                }
            }
        }
    }
#pragma unroll
    for (int j = 0; j < 18; j++) red[(p * 18 + j) * 64 + w] = acc[j];
    __syncthreads();
    for (int idx = t; idx < 18 * 64; idx += 256) {
        const int j  = idx >> 6;
        const int ww = idx & 63;
        float v = red[(0 * 18 + j) * 64 + ww] + red[(1 * 18 + j) * 64 + ww]
                + red[(2 * 18 + j) * 64 + ww] + red[(3 * 18 + j) * 64 + ww];
        v += off_b[g * 18 + j];
        const int k = j >> 1;
        if ((j & 1) == 0) pys[k][ww] = v + (float)(k / 3 - 1) + (float)h;
        else              pxs[k][ww] = v + (float)(k % 3 - 1) + (float)ww;
    }
    __syncthreads();

    float facc[16];
#pragma unroll
    for (int qd = 0; qd < 16; qd++) facc[qd] = 0.0f;
    const int w4 = (t & 15) << 2;
    const int o4 = (t >> 4) << 2;

    for (int k = 0; k < KK; k++) {
#pragma unroll
        for (int n = 0; n < 16; n++) {
            const int v = t + 256 * n;
            const int i = v >> 6;
            const int o = v & 63;
            dwTl[v] = def_w[((g * CG + o) * CG + i) * KK + k];
        }
        const float py  = pys[k][w];
        const float px  = pxs[k][w];
        const float y0f = floorf(py);
        const float x0f = floorf(px);
        const float wy  = py - y0f;
        const float wx  = px - x0f;
        const int   y0  = (int)y0f;
        const int   x0  = (int)x0f;
        const float w00 = (1.0f - wy) * (1.0f - wx);
        const float w01 = (1.0f - wy) * wx;
        const float w10 = wy * (1.0f - wx);
        const float w11 = wy * wx;
        const bool vy0 = (unsigned)y0       < (unsigned)H_;
        const bool vy1 = (unsigned)(y0 + 1) < (unsigned)H_;
        const bool vx0 = (unsigned)x0       < (unsigned)W_;
        const bool vx1 = (unsigned)(x0 + 1) < (unsigned)W_;
        const int a00 = y0 * W_ + x0;
#pragma unroll
        for (int n = 0; n < 16; n++) {
            const int i = (n << 2) + p;
            const float* xi = xg + i * HW;
            const float v00 = (vy0 && vx0) ? xi[a00]          : 0.0f;
            const float v01 = (vy0 && vx1) ? xi[a00 + 1]      : 0.0f;
            const float v10 = (vy1 && vx0) ? xi[a00 + W_]     : 0.0f;
            const float v11 = (vy1 && vx1) ? xi[a00 + W_ + 1] : 0.0f;
            s_lds[i * 64 + w] = w00 * v00 + w01 * v01 + w10 * v10 + w11 * v11;
        }
        __syncthreads();
#pragma unroll 4
        for (int i = 0; i < CG; i++) {
            const float4 sv = *(const float4*)&s_lds[i * 64 + w4];
            const float4 dv = *(const float4*)&dwTl[i * 64 + o4];
            facc[0]  = fmaf(dv.x, sv.x, facc[0]);
            facc[1]  = fmaf(dv.x, sv.y, facc[1]);
            facc[2]  = fmaf(dv.x, sv.z, facc[2]);
            facc[3]  = fmaf(dv.x, sv.w, facc[3]);
            facc[4]  = fmaf(dv.y, sv.x, facc[4]);
            facc[5]  = fmaf(dv.y, sv.y, facc[5]);
            facc[6]  = fmaf(dv.y, sv.z, facc[6]);
            facc[7]  = fmaf(dv.y, sv.w, facc[7]);
            facc[8]  = fmaf(dv.z, sv.x, facc[8]);
            facc[9]  = fmaf(dv.z, sv.y, facc[9]);
            facc[10] = fmaf(dv.z, sv.z, facc[10]);
            facc[11] = fmaf(dv.z, sv.w, facc[11]);
            facc[12] = fmaf(dv.w, sv.x, facc[12]);
            facc[13] = fmaf(dv.w, sv.y, facc[13]);
            facc[14] = fmaf(dv.w, sv.z, facc[14]);
            facc[15] = fmaf(dv.w, sv.w, facc[15]);
        }
        __syncthreads();
    }

    float* outp = out + (size_t)(b * 256 + g * 64) * HW + h * W_;
#pragma unroll
    for (int oo = 0; oo < 4; oo++) {
        const int o = o4 + oo;
        const float bias = def_b[g * 64 + o];
        float4 r;
        r.x = facc[oo * 4 + 0] + bias;
        r.y = facc[oo * 4 + 1] + bias;
        r.z = facc[oo * 4 + 2] + bias;
        r.w = facc[oo * 4 + 3] + bias;
        *(float4*)&outp[o * HW + w4] = r;
    }
}

// ---------------------------------------------------------------------------
extern "C" void kernel_launch(void* const* d_in, const int* in_sizes, int n_in,
                              void* d_out, int out_size, void* d_ws, size_t ws_size,
                              hipStream_t stream)
{
    (void)in_sizes; (void)n_in; (void)out_size;
    const float* x     = (const float*)d_in[0];
    const float* off_w = (const float*)d_in[1];
    const float* off_b = (const float*)d_in[2];
    const float* def_w = (const float*)d_in[3];
    const float* def_b = (const float*)d_in[4];
    float* out = (float*)d_out;

    const size_t xT_bytes  = (size_t)B_ * G_ * XSLICE * 2;     // 37,879,808
    const size_t dw_bytes  = (size_t)G_ * KK * 4096 * 2;       // 294,912
    const size_t ow_bytes  = (size_t)G_ * 18 * 1024 * 2;       // 147,456
    const size_t need = xT_bytes + dw_bytes + ow_bytes;

    const int nblk = B_ * G_ * H_;   // 4096
    const int nprep = G_ * KK * 4096 + G_ * 18 * 1024;   // 221184

    if (ws_size >= need) {
        short* xTpad = (short*)d_ws;
        short* dwA32 = (short*)((char*)d_ws + xT_bytes);
        short* owA   = (short*)((char*)d_ws + xT_bytes + dw_bytes);
        prep_weights<<<(nprep + 255) / 256, 256, 0, stream>>>(off_w, def_w, dwA32, owA);
        prep_x<<<dim3(PD, B_ * G_), 256, 0, stream>>>(x, xTpad);
        deform_main<<<nblk, 256, 0, stream>>>(xTpad, off_b, def_b, dwA32, owA, out);
    } else {
        deform_fallback<<<nblk, 256, 0, stream>>>(x, off_w, off_b, def_w, def_b, out);
    }
}

// Round 5
// 224.287 us; speedup vs baseline: 3.6593x; 1.1588x over previous
//
#include <hip/hip_runtime.h>
#include <hip/hip_bf16.h>

#define B_  16
#define G_  4
#define CG  64
#define H_  64
#define W_  64
#define KK  9
#define HW  (H_ * W_)
#define IP  72            // padded i-stride (shorts) for sT rows: 144 B
#define PD  68            // padded spatial dim (64 + 2 each side)
#define XSLICE (PD * PD * CG)   // shorts per (b,g) slice of xTpad

typedef short  short8  __attribute__((ext_vector_type(8)));
typedef float  f32x4   __attribute__((ext_vector_type(4)));
typedef float  f32x16  __attribute__((ext_vector_type(16)));

__device__ __forceinline__ short f2bf(float v) {
    __hip_bfloat16 hb = __float2bfloat16(v);
    short s;
    __builtin_memcpy(&s, &hb, 2);
    return s;
}

// unpack a u32 holding two bf16 (ch 2j low, 2j+1 high) into float2
__device__ __forceinline__ float2 up2(unsigned int u) {
    union { unsigned int i; float f; } lo, hi;
    lo.i = u << 16;
    hi.i = u & 0xffff0000u;
    return make_float2(lo.f, hi.f);
}

// bilinear combine of 2 packed channels, repacked to 2 bf16 in a u32
__device__ __forceinline__ unsigned int interp2(unsigned int c00, unsigned int c01,
                                                unsigned int c10, unsigned int c11,
                                                float2 w00, float2 w01,
                                                float2 w10, float2 w11) {
    float2 r = up2(c00) * w00 + up2(c01) * w01 + up2(c10) * w10 + up2(c11) * w11;
    __hip_bfloat162 h = __float22bfloat162_rn(r);
    unsigned int o;
    __builtin_memcpy(&o, &h, 4);
    return o;
}

// ---------------------------------------------------------------------------
// Merged prep kernel.
//  blocks [0, 64*68): x -> xTpad[bg][yp][xp][i] bf16, zero borders (pad 2)
//  blocks [64*68, +864): weight prep
//   dwA32[g][k][mt][step][q2][o][e] bf16 = def_w[g][mt*32+o][i=step*16+q2*8+e][k]
//   owA  [g][s][tm][q][jj][e]  bf16 = off_w[g][j=tm*16+jj][(s&1)*32+q*8+e][s>>1]
// ---------------------------------------------------------------------------
__global__ void prep_all(const float* __restrict__ x,
                         const float* __restrict__ off_w,
                         const float* __restrict__ def_w,
                         short* __restrict__ xTpad,
                         short* __restrict__ dwA32,
                         short* __restrict__ owA)
{
    const int blk = blockIdx.x;
    const int t   = threadIdx.x;
    __shared__ float sRow[CG][65];

    if (blk < 64 * PD) {
        const int yp = blk % PD;
        const int bg = blk / PD;
        short* dst = xTpad + (size_t)bg * XSLICE + (size_t)yp * PD * CG;

        if (yp < 2 || yp >= 66) {
            const int4 z = {0, 0, 0, 0};
            for (int c = t; c < (PD * CG * 2) / 16; c += 256)
                ((int4*)dst)[c] = z;
            return;
        }

        const int yy = yp - 2;
        const float* src = x + (size_t)bg * CG * HW + (size_t)yy * W_;
        {
            const int i  = t >> 2;
            const int x0 = (t & 3) * 16;
            const float* sp = src + (size_t)i * HW + x0;
#pragma unroll
            for (int c = 0; c < 4; c++) {
                const float4 v = ((const float4*)sp)[c];
                sRow[i][x0 + c * 4 + 0] = v.x;
                sRow[i][x0 + c * 4 + 1] = v.y;
                sRow[i][x0 + c * 4 + 2] = v.z;
                sRow[i][x0 + c * 4 + 3] = v.w;
            }
        }
        __syncthreads();

        for (int task = t; task < PD * 8; task += 256) {
            const int ich = task & 7;
            const int xp  = task >> 3;
            const int xx  = xp - 2;
            short8 v = {0, 0, 0, 0, 0, 0, 0, 0};
            if ((unsigned)xx < (unsigned)W_) {
#pragma unroll
                for (int e = 0; e < 8; e++) v[e] = f2bf(sRow[ich * 8 + e][xx]);
            }
            *(short8*)(dst + xp * CG + ich * 8) = v;
        }
        return;
    }

    // ---- weights part ----
    const int tid = (blk - 64 * PD) * 256 + t;
    const int ndw = G_ * KK * 4096;               // 147456
    const int now = G_ * 18 * 2 * 4 * 16 * 8;     // 73728
    if (tid < ndw) {
        const int e    = tid & 7;
        const int o    = (tid >> 3) & 31;
        const int q2   = (tid >> 8) & 1;
        const int step = (tid >> 9) & 3;
        const int mt   = (tid >> 11) & 1;
        const int gk   = tid >> 12;
        const int k    = gk % KK;
        const int g    = gk / KK;
        const int oo   = mt * 32 + o;
        const int i    = step * 16 + q2 * 8 + e;
        dwA32[tid] = f2bf(def_w[((g * CG + oo) * CG + i) * KK + k]);
    } else if (tid < ndw + now) {
        const int t2 = tid - ndw;
        const int e  = t2 & 7;
        const int jj = (t2 >> 3) & 15;
        const int q  = (t2 >> 7) & 3;
        const int tm = (t2 >> 9) & 1;
        const int gs = t2 >> 10;
        const int s  = gs % 18;
        const int g  = gs / 18;
        const int j  = tm * 16 + jj;
        const int rc = s >> 1;
        const int i  = (s & 1) * 32 + q * 8 + e;
        owA[t2] = (j < 18) ? f2bf(off_w[((g * 18 + j) * CG + i) * KK + rc]) : (short)0;
    }
}

// ---------------------------------------------------------------------------
// Main fused kernel. Block = (b, g, h) with XCD swizzle. 256 threads, 4 waves.
//  Phase A: offset conv via MFMA 16x16x32 (per spatial tap: 1 addr calc, 2
//           b-frag loads in flight, 4 MFMAs), coords -> pcs[9][64] float2.
//  Phase B: per tap: 16B-wide bf16 gather from xTpad -> sT (double-buffered,
//           packed float2 interpolation), einsum via MFMA 32x32x16.
// ---------------------------------------------------------------------------
__global__ __launch_bounds__(256, 7)
void deform_main(const short* __restrict__ xTpad,
                 const float* __restrict__ off_b,
                 const float* __restrict__ def_b,
                 const short* __restrict__ dwA32,
                 const short* __restrict__ owA,
                 float* __restrict__ out)
{
    const int raw = blockIdx.x;
    const int r8  = raw & 7;
    const int h   = (raw >> 3) & 63;
    const int q8  = raw >> 9;
    const int bg  = q8 * 8 + r8;
    const int b   = bg >> 2;
    const int g   = bg & 3;

    __shared__ float2 pcs[KK][64];          // .x = padded py, .y = padded px
    __shared__ short  sT[2][64 * IP];

    const int t    = threadIdx.x;
    const int lane = t & 63;
    const int p    = t >> 6;          // wave id 0..3
    const int nn   = lane & 15;
    const int q    = lane >> 4;

    const short* xb = xTpad + (size_t)bg * XSLICE;

    // ---------------- Phase A: offset conv (MFMA 16x16x32) ----------------
    {
        const short* owAg = owA + g * 18 * 1024;
        f32x4 oa0 = {0.f, 0.f, 0.f, 0.f};
        f32x4 oa1 = {0.f, 0.f, 0.f, 0.f};
#pragma unroll
        for (int rc = 0; rc < 9; rc++) {
            const int rr = rc / 3;
            const int cc = rc % 3;
            const short* cp = xb + ((h + rr + 1) * PD + (p * 16 + nn + cc + 1)) * CG + q * 8;
            const short8 b0 = *(const short8*)cp;          // s = 2rc   (ih=0)
            const short8 b1 = *(const short8*)(cp + 32);   // s = 2rc+1 (ih=32)
            const int s0 = rc * 2, s1 = rc * 2 + 1;
            const short8 a00 = *(const short8*)(owAg + ((s0 * 2 + 0) * 4 + q) * 128 + nn * 8);
            const short8 a01 = *(const short8*)(owAg + ((s0 * 2 + 1) * 4 + q) * 128 + nn * 8);
            const short8 a10 = *(const short8*)(owAg + ((s1 * 2 + 0) * 4 + q) * 128 + nn * 8);
            const short8 a11 = *(const short8*)(owAg + ((s1 * 2 + 1) * 4 + q) * 128 + nn * 8);
            oa0 = __builtin_amdgcn_mfma_f32_16x16x32_bf16(a00, b0, oa0, 0, 0, 0);
            oa1 = __builtin_amdgcn_mfma_f32_16x16x32_bf16(a01, b0, oa1, 0, 0, 0);
            oa0 = __builtin_amdgcn_mfma_f32_16x16x32_bf16(a10, b1, oa0, 0, 0, 0);
            oa1 = __builtin_amdgcn_mfma_f32_16x16x32_bf16(a11, b1, oa1, 0, 0, 0);
        }
        // C layout: col = nn (w within tile), row = q*4 + reg (j)
        const int n = p * 16 + nn;
#pragma unroll
        for (int reg = 0; reg < 4; reg++) {
            const int j  = q * 4 + reg;
            const int kk = j >> 1;
            const float v = oa0[reg] + off_b[g * 18 + j];
            if ((j & 1) == 0) pcs[kk][n].x = v + (float)(kk / 3) + (float)(h + 1);
            else              pcs[kk][n].y = v + (float)(kk % 3) + (float)(n + 1);
        }
        if (q == 0) {
            pcs[8][n].x = oa1[0] + off_b[g * 18 + 16] + 2.0f + (float)(h + 1);
            pcs[8][n].y = oa1[1] + off_b[g * 18 + 17] + 2.0f + (float)(n + 1);
        }
        // each wave reads only its own tile's coords in the gather: no barrier
    }

    // ---------------- Phase B: gather + einsum, double-buffered ----------------
    const int mt  = p >> 1;           // einsum output 32-row tile
    const int nt  = p & 1;            // einsum output 32-col tile
    const int n31 = lane & 31;
    const int q2  = lane >> 5;

    f32x16 acc = {0.f};
    const short* dwg = dwA32 + g * KK * 4096;

    const int posL  = lane >> 3;      // 0..7: position within 8-group
    const int chidx = lane & 7;       // 8-channel chunk

    // gather of one tap into buffer sTb: 8 lanes/pos, 8 ch/lane, 16B loads
    auto gather_tap = [&](int k, short* __restrict__ sTb) {
#pragma unroll
        for (int it = 0; it < 2; it++) {
            const int pos = p * 16 + it * 8 + posL;
            const float2 pc = pcs[k][pos];
            const float yf = floorf(pc.x);
            const float xf = floorf(pc.y);
            const float wy = pc.x - yf;
            const float wx = pc.y - xf;
            int y0 = (int)yf;
            int x0 = (int)xf;
            y0 = (y0 < 0) ? 0 : ((y0 > 66) ? 66 : y0);
            x0 = (x0 < 0) ? 0 : ((x0 > 66) ? 66 : x0);
            const short* cp = xb + (y0 * PD + x0) * CG + chidx * 8;
            const uint4 c00 = *(const uint4*)cp;
            const uint4 c01 = *(const uint4*)(cp + CG);
            const uint4 c10 = *(const uint4*)(cp + PD * CG);
            const uint4 c11 = *(const uint4*)(cp + PD * CG + CG);
            const float a00 = (1.0f - wy) * (1.0f - wx);
            const float a01 = (1.0f - wy) * wx;
            const float a10 = wy * (1.0f - wx);
            const float a11 = wy * wx;
            const float2 w00 = make_float2(a00, a00);
            const float2 w01 = make_float2(a01, a01);
            const float2 w10 = make_float2(a10, a10);
            const float2 w11 = make_float2(a11, a11);
            uint4 ov;
            ov.x = interp2(c00.x, c01.x, c10.x, c11.x, w00, w01, w10, w11);
            ov.y = interp2(c00.y, c01.y, c10.y, c11.y, w00, w01, w10, w11);
            ov.z = interp2(c00.z, c01.z, c10.z, c11.z, w00, w01, w10, w11);
            ov.w = interp2(c00.w, c01.w, c10.w, c11.w, w00, w01, w10, w11);
            *(uint4*)&sTb[pos * IP + chidx * 8] = ov;
        }
    };

    // einsum of one tap from buffer sTb (MFMA 32x32x16)
    auto einsum_tap = [&](int k, const short* __restrict__ sTb) {
        const short* dwk = dwg + k * 4096;
#pragma unroll
        for (int step = 0; step < 4; step++) {
            const short8 af = *(const short8*)(dwk + ((mt * 4 + step) * 2 + q2) * 256 + n31 * 8);
            const short8 bf = *(const short8*)&sTb[(nt * 32 + n31) * IP + step * 16 + q2 * 8];
            acc = __builtin_amdgcn_mfma_f32_32x32x16_bf16(af, bf, acc, 0, 0, 0);
        }
    };

    gather_tap(0, &sT[0][0]);
    __syncthreads();
    for (int k = 0; k < KK; k++) {
        if (k < KK - 1) gather_tap(k + 1, &sT[(k + 1) & 1][0]);
        einsum_tap(k, &sT[k & 1][0]);
        __syncthreads();
    }

    // ---------------- epilogue ----------------
    // C/D 32x32 layout: col = lane&31, row = (reg&3) + 8*(reg>>2) + 4*q2
    float* outb = out + (size_t)(b * 256 + g * 64) * HW + h * W_;
    const int n = nt * 32 + n31;
#pragma unroll
    for (int reg = 0; reg < 16; reg++) {
        const int o = mt * 32 + (reg & 3) + 8 * (reg >> 2) + 4 * q2;
        outb[(size_t)o * HW + n] = acc[reg] + def_b[g * 64 + o];
    }
}

// ---------------------------------------------------------------------------
// Fallback (no workspace): round-1-style fused fp32 kernel, known correct.
// ---------------------------------------------------------------------------
__global__ __launch_bounds__(256, 4)
void deform_fallback(const float* __restrict__ x,
                     const float* __restrict__ off_w,
                     const float* __restrict__ off_b,
                     const float* __restrict__ def_w,
                     const float* __restrict__ def_b,
                     float* __restrict__ out)
{
    const int raw = blockIdx.x;
    const int r8  = raw & 7;
    const int h   = (raw >> 3) & 63;
    const int q8  = raw >> 9;
    const int bg  = q8 * 8 + r8;
    const int b   = bg >> 2;
    const int g   = bg & 3;

    __shared__ float pys[KK][W_];
    __shared__ float pxs[KK][W_];
    __shared__ float buf[8192];
    float* red   = buf;
    float* s_lds = buf;
    float* dwTl  = buf + 4096;

    const int t = threadIdx.x;
    const int w = t & 63;
    const int p = t >> 6;

    const float* xg = x + (size_t)(b * 256 + g * 64) * HW;

    float acc[18];
#pragma unroll
    for (int j = 0; j < 18; j++) acc[j] = 0.0f;
    {
        const int i0 = p * 16;
        for (int ii = 0; ii < 16; ii++) {
            const int i = i0 + ii;
            const float* xi = xg + i * HW;
#pragma unroll
            for (int r = 0; r < 3; r++) {
                const int y = h + r - 1;
                if ((unsigned)y >= (unsigned)H_) continue;
#pragma unroll
                for (int c = 0; c < 3; c++) {
                    const int xc = w + c - 1;
                    const float xv = ((unsigned)xc < (unsigned)W_) ? xi[y * W_ + xc] : 0.0f;
#pragma unroll
                    for (int j = 0; j < 18; j++) {
                        const float wv = off_w[((g * 18 + j) * CG + i) * 9 + r * 3 + c];
                        acc[j] = fmaf(wv, xv, acc[j]);
                    }
                }
            }
        }
    }
#pragma unroll
    for (int j = 0; j < 18; j++) red[(p * 18 + j) * 64 + w] = acc[j];
    __syncthreads();
    for (int idx = t; idx < 18 * 64; idx += 256) {
        const int j  = idx >> 6;
        const int ww = idx & 63;
        float v = red[(0 * 18 + j) * 64 + ww] + red[(1 * 18 + j) * 64 + ww]
                + red[(2 * 18 + j) * 64 + ww] + red[(3 * 18 + j) * 64 + ww];
        v += off_b[g * 18 + j];
        const int k = j >> 1;
        if ((j & 1) == 0) pys[k][ww] = v + (float)(k / 3 - 1) + (float)h;
        else              pxs[k][ww] = v + (float)(k % 3 - 1) + (float)ww;
    }
    __syncthreads();

    float facc[16];
#pragma unroll
    for (int qd = 0; qd < 16; qd++) facc[qd] = 0.0f;
    const int w4 = (t & 15) << 2;
    const int o4 = (t >> 4) << 2;

    for (int k = 0; k < KK; k++) {
#pragma unroll
        for (int n = 0; n < 16; n++) {
            const int v = t + 256 * n;
            const int i = v >> 6;
            const int o = v & 63;
            dwTl[v] = def_w[((g * CG + o) * CG + i) * KK + k];
        }
        const float py  = pys[k][w];
        const float px  = pxs[k][w];
        const float y0f = floorf(py);
        const float x0f = floorf(px);
        const float wy  = py - y0f;
        const float wx  = px - x0f;
        const int   y0  = (int)y0f;
        const int   x0  = (int)x0f;
        const float w00 = (1.0f - wy) * (1.0f - wx);
        const float w01 = (1.0f - wy) * wx;
        const float w10 = wy * (1.0f - wx);
        const float w11 = wy * wx;
        const bool vy0 = (unsigned)y0       < (unsigned)H_;
        const bool vy1 = (unsigned)(y0 + 1) < (unsigned)H_;
        const bool vx0 = (unsigned)x0       < (unsigned)W_;
        const bool vx1 = (unsigned)(x0 + 1) < (unsigned)W_;
        const int a00 = y0 * W_ + x0;
#pragma unroll
        for (int n = 0; n < 16; n++) {
            const int i = (n << 2) + p;
            const float* xi = xg + i * HW;
            const float v00 = (vy0 && vx0) ? xi[a00]          : 0.0f;
            const float v01 = (vy0 && vx1) ? xi[a00 + 1]      : 0.0f;
            const float v10 = (vy1 && vx0) ? xi[a00 + W_]     : 0.0f;
            const float v11 = (vy1 && vx1) ? xi[a00 + W_ + 1] : 0.0f;
            s_lds[i * 64 + w] = w00 * v00 + w01 * v01 + w10 * v10 + w11 * v11;
        }
        __syncthreads();
#pragma unroll 4
        for (int i = 0; i < CG; i++) {
            const float4 sv = *(const float4*)&s_lds[i * 64 + w4];
            const float4 dv = *(const float4*)&dwTl[i * 64 + o4];
            facc[0]  = fmaf(dv.x, sv.x, facc[0]);
            facc[1]  = fmaf(dv.x, sv.y, facc[1]);
            facc[2]  = fmaf(dv.x, sv.z, facc[2]);
            facc[3]  = fmaf(dv.x, sv.w, facc[3]);
            facc[4]  = fmaf(dv.y, sv.x, facc[4]);
            facc[5]  = fmaf(dv.y, sv.y, facc[5]);
            facc[6]  = fmaf(dv.y, sv.z, facc[6]);
            facc[7]  = fmaf(dv.y, sv.w, facc[7]);
            facc[8]  = fmaf(dv.z, sv.x, facc[8]);
            facc[9]  = fmaf(dv.z, sv.y, facc[9]);
            facc[10] = fmaf(dv.z, sv.z, facc[10]);
            facc[11] = fmaf(dv.z, sv.w, facc[11]);
            facc[12] = fmaf(dv.w, sv.x, facc[12]);
            facc[13] = fmaf(dv.w, sv.y, facc[13]);
            facc[14] = fmaf(dv.w, sv.z, facc[14]);
            facc[15] = fmaf(dv.w, sv.w, facc[15]);
        }
        __syncthreads();
    }

    float* outp = out + (size_t)(b * 256 + g * 64) * HW + h * W_;
#pragma unroll
    for (int oo = 0; oo < 4; oo++) {
        const int o = o4 + oo;
        const float bias = def_b[g * 64 + o];
        float4 r;
        r.x = facc[oo * 4 + 0] + bias;
        r.y = facc[oo * 4 + 1] + bias;
        r.z = facc[oo * 4 + 2] + bias;
        r.w = facc[oo * 4 + 3] + bias;
        *(float4*)&outp[o * HW + w4] = r;
    }
}

// ---------------------------------------------------------------------------
extern "C" void kernel_launch(void* const* d_in, const int* in_sizes, int n_in,
                              void* d_out, int out_size, void* d_ws, size_t ws_size,
                              hipStream_t stream)
{
    (void)in_sizes; (void)n_in; (void)out_size;
    const float* x     = (const float*)d_in[0];
    const float* off_w = (const float*)d_in[1];
    const float* off_b = (const float*)d_in[2];
    const float* def_w = (const float*)d_in[3];
    const float* def_b = (const float*)d_in[4];
    float* out = (float*)d_out;

    const size_t xT_bytes  = (size_t)B_ * G_ * XSLICE * 2;     // 37,879,808
    const size_t dw_bytes  = (size_t)G_ * KK * 4096 * 2;       // 294,912
    const size_t ow_bytes  = (size_t)G_ * 18 * 1024 * 2;       // 147,456
    const size_t need = xT_bytes + dw_bytes + ow_bytes;

    const int nblk   = B_ * G_ * H_;                     // 4096
    const int nprepw = (G_ * KK * 4096 + G_ * 18 * 1024 + 255) / 256;  // 864
    const int nprep  = 64 * PD + nprepw;                 // 4352 + 864

    if (ws_size >= need) {
        short* xTpad = (short*)d_ws;
        short* dwA32 = (short*)((char*)d_ws + xT_bytes);
        short* owA   = (short*)((char*)d_ws + xT_bytes + dw_bytes);
        prep_all<<<nprep, 256, 0, stream>>>(x, off_w, def_w, xTpad, dwA32, owA);
        deform_main<<<nblk, 256, 0, stream>>>(xTpad, off_b, def_b, dwA32, owA, out);
    } else {
        deform_fallback<<<nblk, 256, 0, stream>>>(x, off_w, off_b, def_w, def_b, out);
    }
}